// Round 8
// baseline (173.139 us; speedup 1.0000x reference)
//
#include <hip/hip_runtime.h>
#include <cstddef>
#include <cstdint>

#define B_ 2
#define S_ 2048
#define DM_ 1024
#define H_ 16
#define DH_ 64
#define NEGV (-1e12f)
// log2(e) / sqrt(DH) folded into Q at projection epilogue
#define QSCALE 0.18033688011112042f
// defer-max threshold in log2 units: P <= 2^12, l <= 2048*4096 -> fp32-safe
#define DEFER_THR 12.0f

typedef __attribute__((ext_vector_type(8))) short bf16x8;
typedef __attribute__((ext_vector_type(4))) float f32x4;
typedef __attribute__((ext_vector_type(16))) float f32x16;

__device__ __forceinline__ unsigned short f2bf(float f) {
    union { float f; uint32_t u; } v; v.f = f;
    uint32_t u = v.u;
    u += 0x7FFF + ((u >> 16) & 1);   // round-to-nearest-even
    return (unsigned short)(u >> 16);
}

// packed f32x2 -> bf16x2 (RNE), single HW instruction (T12 recipe)
__device__ __forceinline__ uint32_t cvt_pk_bf16(float lo, float hi) {
    uint32_t r;
    asm volatile("v_cvt_pk_bf16_f32 %0, %1, %2" : "=v"(r) : "v"(lo), "v"(hi));
    return r;
}

__device__ __forceinline__ void gload_lds16(const void* g, void* l) {
    __builtin_amdgcn_global_load_lds(
        (__attribute__((address_space(1))) void*)g,
        (__attribute__((address_space(3))) void*)l,
        16, 0, 0);
}

// ---------------------------------------------------------------------------
// x (fp32) -> bf16, flat
// ---------------------------------------------------------------------------
__global__ __launch_bounds__(256) void convx_kernel(
    const float* __restrict__ x, ushort* __restrict__ xb)
{
    const size_t i = ((size_t)blockIdx.x * 256 + threadIdx.x) * 8;
    const float4 a = *(const float4*)(x + i);
    const float4 b = *(const float4*)(x + i + 4);
    ushort4 u0, u1;
    u0.x = f2bf(a.x); u0.y = f2bf(a.y); u0.z = f2bf(a.z); u0.w = f2bf(a.w);
    u1.x = f2bf(b.x); u1.y = f2bf(b.y); u1.z = f2bf(b.z); u1.w = f2bf(b.w);
    *(ushort4*)(xb + i) = u0;
    *(ushort4*)(xb + i + 4) = u1;
}

// ---------------------------------------------------------------------------
// batched: W[k][n] fp32 -> Wt[n][k] bf16 for all 4 weights in one launch
// ---------------------------------------------------------------------------
__global__ __launch_bounds__(256) void wconv_all_kernel(
    const float* __restrict__ W0, const float* __restrict__ W1,
    const float* __restrict__ W2, const float* __restrict__ W3,
    ushort* __restrict__ T0, ushort* __restrict__ T1,
    ushort* __restrict__ T2, ushort* __restrict__ T3)
{
    __shared__ float T[64][65];
    const int tid = threadIdx.x;
    const int sel = blockIdx.x >> 8;
    const int bt  = blockIdx.x & 255;
    const float* W = (sel == 0) ? W0 : (sel == 1) ? W1 : (sel == 2) ? W2 : W3;
    ushort* Wt = (sel == 0) ? T0 : (sel == 1) ? T1 : (sel == 2) ? T2 : T3;

    const int n0 = (bt & 15) * 64;
    const int k0 = (bt >> 4) * 64;
    const int tr = tid >> 4, tc = tid & 15;
#pragma unroll
    for (int i = 0; i < 4; ++i) {
        const float4 v = *(const float4*)(W + (size_t)(k0 + tr + i * 16) * 1024 + n0 + tc * 4);
        T[tr + i * 16][tc * 4 + 0] = v.x;
        T[tr + i * 16][tc * 4 + 1] = v.y;
        T[tr + i * 16][tc * 4 + 2] = v.z;
        T[tr + i * 16][tc * 4 + 3] = v.w;
    }
    __syncthreads();
    const int orr = tid >> 2, oc = tid & 3;
#pragma unroll
    for (int j = 0; j < 4; ++j) {
        ushort4 u;
        u.x = f2bf(T[oc * 16 + j * 4 + 0][orr]);
        u.y = f2bf(T[oc * 16 + j * 4 + 1][orr]);
        u.z = f2bf(T[oc * 16 + j * 4 + 2][orr]);
        u.w = f2bf(T[oc * 16 + j * 4 + 3][orr]);
        *(ushort4*)(Wt + (size_t)(n0 + orr) * 1024 + k0 + oc * 16 + j * 4) = u;
    }
}

// ---------------------------------------------------------------------------
// bf16 MFMA GEMM, C = A @ Bt^T (+bias, +epilogue). A[M][1024], Bt[n][1024].
// MODE 1: fused QKV (BM=128, Ntot=3072 in 3 segments; rope epilogues, V transp)
// MODE 0: out-proj  (BM=64, N=1024, fp32 out)
// (unchanged — validated)
// ---------------------------------------------------------------------------
template <int MODE>
__global__ __launch_bounds__(256) void gemm_bf16(
    const ushort* __restrict__ A,
    const ushort* __restrict__ B0, const ushort* __restrict__ B1, const ushort* __restrict__ B2,
    const float* __restrict__ bias0, const float* __restrict__ bias1, const float* __restrict__ bias2,
    const float* __restrict__ pos,
    void* __restrict__ o0, void* __restrict__ o1, void* __restrict__ o2)
{
    constexpr int BM = MODE ? 128 : 64;
    constexpr int BN = 128;
    constexpr int NTN = MODE ? 24 : 8;
    constexpr int A_ISS = BM / 64;
    constexpr int ABYTES = BM * 64;
    constexpr int WM = MODE ? 2 : 1;
    constexpr int TM = BM / WM;
    constexpr int TN = BN / (4 / WM);
    constexpr int MI = TM / 16;
    constexpr int NJ = TN / 16;
    constexpr int NT = DM_ / 32;

    __shared__ char lds[2][(BM + BN) * 64];

    const int tid  = threadIdx.x;
    const int lane = tid & 63;
    const int lc = lane & 15, lg = lane >> 4;
    const int w  = tid >> 6;
    const int wm = MODE ? (w >> 1) : 0;
    const int wn = MODE ? (w & 1) : w;

    const int ntile = blockIdx.x % NTN;
    const int mtile = blockIdx.x / NTN;
    const int m0 = mtile * BM;

    int seg = 0, nseg0 = ntile * 128;
    const ushort* Bt = B0;
    const float* biasp = bias0;
    if constexpr (MODE == 1) {
        seg = ntile >> 3;
        nseg0 = (ntile & 7) * 128;
        Bt = (seg == 0) ? B0 : (seg == 1) ? B1 : B2;
        biasp = (seg == 0) ? bias0 : (seg == 1) ? bias1 : bias2;
    }

    const int sr = tid >> 2;
    const int sc = (tid & 3) * 8;
    const int wub = (tid & 0xC0) * 16;

#define STAGE(BUF, KT)                                                             \
    do {                                                                           \
        const int k0s = (KT) * 32;                                                 \
        char* lb = &lds[BUF][0];                                                   \
        _Pragma("unroll")                                                          \
        for (int ii = 0; ii < A_ISS; ++ii)                                         \
            gload_lds16(A + (size_t)(m0 + ii * 64 + sr) * DM_ + k0s + sc,          \
                        lb + ii * 4096 + wub);                                     \
        _Pragma("unroll")                                                          \
        for (int ii = 0; ii < 2; ++ii)                                             \
            gload_lds16(Bt + (size_t)(nseg0 + ii * 64 + sr) * DM_ + k0s + sc,      \
                        lb + ABYTES + ii * 4096 + wub);                            \
    } while (0)

    f32x4 acc[MI][NJ];
#pragma unroll
    for (int mi = 0; mi < MI; ++mi)
#pragma unroll
        for (int nj = 0; nj < NJ; ++nj) acc[mi][nj] = (f32x4){0.f, 0.f, 0.f, 0.f};

    STAGE(0, 0);

    for (int kt = 0; kt < NT; ++kt) {
        const int cur = kt & 1;
        __syncthreads();
        if (kt + 1 < NT) STAGE(cur ^ 1, kt + 1);
        const char* Ab = &lds[cur][0];
        const char* Bb = Ab + ABYTES;
        bf16x8 af[MI], bfr[NJ];
#pragma unroll
        for (int mi = 0; mi < MI; ++mi)
            af[mi] = *(const bf16x8*)(Ab + (wm * TM + mi * 16 + lc) * 64 + lg * 16);
#pragma unroll
        for (int nj = 0; nj < NJ; ++nj)
            bfr[nj] = *(const bf16x8*)(Bb + (wn * TN + nj * 16 + lc) * 64 + lg * 16);
#pragma unroll
        for (int mi = 0; mi < MI; ++mi)
#pragma unroll
            for (int nj = 0; nj < NJ; ++nj)
                acc[mi][nj] = __builtin_amdgcn_mfma_f32_16x16x32_bf16(af[mi], bfr[nj], acc[mi][nj], 0, 0, 0);
    }
#undef STAGE

    if constexpr (MODE == 0) {
        float* C = (float*)o0;
#pragma unroll
        for (int nj = 0; nj < NJ; ++nj) {
            const int n = nseg0 + wn * TN + nj * 16 + lc;
            const float bn = biasp[n];
#pragma unroll
            for (int mi = 0; mi < MI; ++mi)
#pragma unroll
                for (int r = 0; r < 4; ++r) {
                    const int m = m0 + wm * TM + mi * 16 + lg * 4 + r;
                    C[(size_t)m * DM_ + n] = acc[mi][nj][r] + bn;
                }
        }
    } else {
        if (seg < 2) {
            ushort* C = (seg == 0) ? (ushort*)o0 : (ushort*)o1;
#pragma unroll
            for (int nj = 0; nj < NJ; ++nj) {
                const int n = nseg0 + wn * TN + nj * 16 + lc;
                const float bn = biasp[n];
                const int i2 = (n & 63) & ~1;
                const bool odd = (n & 1) != 0;
#pragma unroll
                for (int mi = 0; mi < MI; ++mi)
#pragma unroll
                    for (int r = 0; r < 4; ++r) {
                        const int m = m0 + wm * TM + mi * 16 + lg * 4 + r;
                        const int s = m & (S_ - 1);
                        const float2 pz = *(const float2*)(pos + (size_t)s * DH_ + i2);
                        const float v = acc[mi][nj][r] + bn;
                        const float pv = __shfl_xor(v, 1);
                        float ov = odd ? (v * pz.y + pv * pz.x) : (v * pz.y - pv * pz.x);
                        if (seg == 0) ov *= QSCALE;
                        C[(size_t)m * (H_ * DH_) + n] = f2bf(ov);
                    }
            }
        } else {
            ushort* C = (ushort*)o2;
#pragma unroll
            for (int nj = 0; nj < NJ; ++nj) {
                const int n = nseg0 + wn * TN + nj * 16 + lc;
                const int hh = n >> 6, dd = n & 63;
                const float bn = biasp[n];
#pragma unroll
                for (int mi = 0; mi < MI; ++mi) {
                    const int mb = m0 + wm * TM + mi * 16 + lg * 4;
                    const int bb = mb >> 11, ss = mb & (S_ - 1);
                    ushort4 u;
                    u.x = f2bf(acc[mi][nj][0] + bn);
                    u.y = f2bf(acc[mi][nj][1] + bn);
                    u.z = f2bf(acc[mi][nj][2] + bn);
                    u.w = f2bf(acc[mi][nj][3] + bn);
                    *(ushort4*)(C + ((size_t)(bb * H_ + hh) * DH_ + dd) * S_ + ss) = u;
                }
            }
        }
    }
}

// ---------------------------------------------------------------------------
// bf16 MFMA flash attention — round 8: 32x32 MFMA tile, 8 waves x 32 q = 256
// q-rows per block (m214 structure).
// Swapped QK^T: acc_t[kb] = mfma_32x32x16(K,Q) -> S[key][q], q = lane&31:
// each lane owns the full 64-key score row for one q (split across hi-half).
// Softmax: in-lane tree + ONE shfl_xor(32). PV as mfma(V^T, P) -> O^T[d][q]:
// rescale and 1/l are fully lane-local (zero shuffles).
// P->B-frag: 16 cvt_pk + half-exchange via shfl_xor(32)+select.
// C/D layout 32x32: col=lane&31, row=(reg&3)+8*(reg>>2)+4*(lane>>5) [m74/m101];
// A/B frag: row/col=lane&31, k=(lane>>5)*8+j.
// Same double-buffered 2-barrier pipeline (QK one tile ahead) as validated.
// ---------------------------------------------------------------------------
__global__ __launch_bounds__(512, 2) void attn_mfma_kernel(
    const short* __restrict__ Qb, const short* __restrict__ Kb,
    const short* __restrict__ Vt, const int* __restrict__ vmask,
    ushort* __restrict__ O)
{
    __shared__ short Ks[2][64 * 64];
    __shared__ short Vs[2][64 * 64];
    __shared__ float bias_s[2][64];

    const int tid  = threadIdx.x;
    const int lane = tid & 63;
    const int w    = tid >> 6;        // 0..7
    const int l31  = lane & 31;
    const int hi   = lane >> 5;

    const int bid = blockIdx.x;       // b*128 + h*8 + qc (qc low: K/V L2 reuse)
    const int qc = bid & 7;
    const int h  = (bid >> 3) & 15;
    const int b  = bid >> 7;
    const int qrow = qc * 256 + w * 32 + l31;

    // Q B-frags: qf[ks] holds Q[q=qrow][k = ks*16 + hi*8 + j]
    bf16x8 qf[4];
    {
        const size_t qbase = ((size_t)(b * S_ + qrow)) * DM_ + h * DH_ + hi * 8;
        qf[0] = *(const bf16x8*)(Qb + qbase);
        qf[1] = *(const bf16x8*)(Qb + qbase + 16);
        qf[2] = *(const bf16x8*)(Qb + qbase + 32);
        qf[3] = *(const bf16x8*)(Qb + qbase + 48);
    }

    // staging: 512 threads, one 16B chunk per thread per matrix
    const int kr0 = tid >> 3, kc0 = tid & 7;
    const size_t kpan = ((size_t)b * S_) * DM_ + h * DH_;
    const size_t vpan = ((size_t)(b * H_ + h) * DH_) * S_;

    uint4 kv0, vv0;
    int mskv = 1;
    constexpr int NT = S_ / 64;

#define LOAD_TILE(KT)                                                            \
    do {                                                                         \
        kv0 = *(const uint4*)(Kb + kpan + (size_t)((KT) * 64 + kr0) * DM_ + kc0 * 8); \
        vv0 = *(const uint4*)(Vt + vpan + (size_t)kr0 * S_ + (KT) * 64 + kc0 * 8);    \
        if (tid < 64) mskv = vmask[b * S_ + (KT) * 64 + tid];                    \
    } while (0)

#define STORE_TILE(BUF)                                                          \
    do {                                                                         \
        *(uint4*)&Ks[BUF][kr0 * 64 + ((kc0 ^ (kr0 & 7)) * 8)] = kv0;             \
        *(uint4*)&Vs[BUF][kr0 * 64 + ((kc0 ^ (kr0 & 7)) * 8)] = vv0;             \
        if (tid < 64) bias_s[BUF][tid] = mskv ? 0.f : NEGV;                      \
    } while (0)

// QK^T (swapped): ACC[kb][reg] = S[key = kb*32 + (reg&3)+8*(reg>>2)+4*hi][q],
// init with mask bias (quad g <- bias[kb*32 + 8g + 4hi .. +3])
#define QK_TILE(ACC, BUF)                                                        \
    do {                                                                         \
        _Pragma("unroll")                                                        \
        for (int kb = 0; kb < 2; ++kb) {                                         \
            union { f32x16 v; f32x4 q[4]; } tb;                                  \
            _Pragma("unroll")                                                    \
            for (int g = 0; g < 4; ++g)                                          \
                tb.q[g] = *(const f32x4*)&bias_s[BUF][kb * 32 + 8 * g + 4 * hi]; \
            ACC[kb] = tb.v;                                                      \
        }                                                                        \
        _Pragma("unroll")                                                        \
        for (int ks = 0; ks < 4; ++ks)                                           \
            _Pragma("unroll")                                                    \
            for (int kb = 0; kb < 2; ++kb) {                                     \
                const int key = kb * 32 + l31;                                   \
                const bf16x8 kf = *(const bf16x8*)&Ks[BUF][key * 64 +            \
                                        (((ks * 2 + hi) ^ (key & 7)) * 8)];      \
                ACC[kb] = __builtin_amdgcn_mfma_f32_32x32x16_bf16(               \
                              kf, qf[ks], ACC[kb], 0, 0, 0);                     \
            }                                                                    \
    } while (0)

// softmax (defer-max, lane-local stats) + P->bf16 + half-exchange + PV
#define SOFTMAX_PV(ACC, BUF)                                                     \
    do {                                                                         \
        float t8[8];                                                             \
        _Pragma("unroll")                                                        \
        for (int i = 0; i < 8; ++i)                                              \
            t8[i] = fmaxf(fmaxf(ACC[0][i], ACC[0][i + 8]),                       \
                          fmaxf(ACC[1][i], ACC[1][i + 8]));                      \
        float pm = fmaxf(fmaxf(fmaxf(t8[0], t8[4]), fmaxf(t8[1], t8[5])),        \
                         fmaxf(fmaxf(t8[2], t8[6]), fmaxf(t8[3], t8[7])));       \
        pm = fmaxf(pm, __shfl_xor(pm, 32));                                      \
        if (!__all(pm <= m_run + DEFER_THR)) {                                   \
            const float m_new = fmaxf(m_run, pm);                                \
            const float sc = exp2f(m_run - m_new);                               \
            acc_o[0] *= sc;                                                      \
            acc_o[1] *= sc;                                                      \
            l_run *= sc;                                                         \
            m_run = m_new;                                                       \
        }                                                                        \
        uint32_t pk[2][4][2];                                                    \
        float tsum = 0.f;                                                        \
        _Pragma("unroll")                                                        \
        for (int kb = 0; kb < 2; ++kb)                                           \
            _Pragma("unroll")                                                    \
            for (int g = 0; g < 4; ++g) {                                        \
                const float e0 = exp2f(ACC[kb][4 * g + 0] - m_run);              \
                const float e1 = exp2f(ACC[kb][4 * g + 1] - m_run);              \
                const float e2 = exp2f(ACC[kb][4 * g + 2] - m_run);              \
                const float e3 = exp2f(ACC[kb][4 * g + 3] - m_run);              \
                tsum += (e0 + e1) + (e2 + e3);                                   \
                pk[kb][g][0] = cvt_pk_bf16(e0, e1);                              \
                pk[kb][g][1] = cvt_pk_bf16(e2, e3);                              \
            }                                                                    \
        tsum += __shfl_xor(tsum, 32);                                            \
        l_run += tsum;                                                           \
        _Pragma("unroll")                                                        \
        for (int ks = 0; ks < 4; ++ks) {                                         \
            const int kb2 = ks >> 1, s16 = ks & 1;                               \
            const uint32_t A0 = pk[kb2][2 * s16][0],  A1 = pk[kb2][2 * s16][1];  \
            const uint32_t B0 = pk[kb2][2 * s16 + 1][0], B1 = pk[kb2][2 * s16 + 1][1]; \
            const uint32_t sA0 = __shfl_xor(A0, 32), sA1 = __shfl_xor(A1, 32);   \
            const uint32_t sB0 = __shfl_xor(B0, 32), sB1 = __shfl_xor(B1, 32);   \
            union { uint32_t u[4]; bf16x8 v; } pf;                               \
            pf.u[0] = hi ? sB0 : A0;                                             \
            pf.u[1] = hi ? sB1 : A1;                                             \
            pf.u[2] = hi ? B0 : sA0;                                             \
            pf.u[3] = hi ? B1 : sA1;                                             \
            _Pragma("unroll")                                                    \
            for (int db = 0; db < 2; ++db) {                                     \
                const int d = db * 32 + l31;                                     \
                const bf16x8 vf = *(const bf16x8*)&Vs[BUF][d * 64 +              \
                                        (((ks * 2 + hi) ^ (d & 7)) * 8)];        \
                acc_o[db] = __builtin_amdgcn_mfma_f32_32x32x16_bf16(             \
                                vf, pf.v, acc_o[db], 0, 0, 0);                   \
            }                                                                    \
        }                                                                        \
    } while (0)

    float m_run = -1e30f, l_run = 0.f;
    f32x16 acc_o[2];
    acc_o[0] = (f32x16)(0.f);
    acc_o[1] = (f32x16)(0.f);

    // ---- prologue: tile 0 into buf0, QK(0)
    LOAD_TILE(0);
    STORE_TILE(0);
    __syncthreads();
    LOAD_TILE(1);
    f32x16 acc_t[2];
    QK_TILE(acc_t, 0);

    // ---- main loop: iteration kt issues QK(kt+1), finishes tile kt
    for (int kt = 0; kt < NT - 1; ++kt) {
        const int cur = kt & 1, nxt = cur ^ 1;
        STORE_TILE(nxt);                       // regs hold tile kt+1
        __syncthreads();
        if (kt + 2 < NT) LOAD_TILE(kt + 2);    // prefetch tile kt+2 into regs
        f32x16 acc_n[2];
        QK_TILE(acc_n, nxt);                   // MFMA pipe: scores(kt+1)
        SOFTMAX_PV(acc_t, cur);                // VALU overlaps MFMA above
        acc_t[0] = acc_n[0];
        acc_t[1] = acc_n[1];
        __syncthreads();                       // protect buf[cur] before overwrite
    }
    // ---- epilogue: finish last tile
    SOFTMAX_PV(acc_t, (NT - 1) & 1);

#undef LOAD_TILE
#undef STORE_TILE
#undef QK_TILE
#undef SOFTMAX_PV

    // ---- normalize and write O (bf16); all lane-local
    const float linv = 1.0f / l_run;
    const size_t ob = ((size_t)(b * S_ + qrow)) * DM_ + h * DH_;
#pragma unroll
    for (int db = 0; db < 2; ++db)
#pragma unroll
        for (int g = 0; g < 4; ++g) {
            const int dbase = db * 32 + 8 * g + 4 * hi;
            uint2 ww;
            ww.x = cvt_pk_bf16(acc_o[db][4 * g + 0] * linv, acc_o[db][4 * g + 1] * linv);
            ww.y = cvt_pk_bf16(acc_o[db][4 * g + 2] * linv, acc_o[db][4 * g + 3] * linv);
            *(uint2*)(O + ob + dbase) = ww;
        }
}

// ---------------------------------------------------------------------------
extern "C" void kernel_launch(void* const* d_in, const int* in_sizes, int n_in,
                              void* d_out, int out_size, void* d_ws, size_t ws_size,
                              hipStream_t stream)
{
    const float* x     = (const float*)d_in[0];
    const int*   vmask = (const int*)d_in[1];
    const float* pos   = (const float*)d_in[2];
    const float* Wq    = (const float*)d_in[3];
    const float* bq    = (const float*)d_in[4];
    const float* Wk    = (const float*)d_in[5];
    const float* bk    = (const float*)d_in[6];
    const float* Wv    = (const float*)d_in[7];
    const float* bv    = (const float*)d_in[8];
    const float* Wo    = (const float*)d_in[9];
    const float* bo    = (const float*)d_in[10];
    float* out = (float*)d_out;

    const size_t MN = (size_t)(B_ * S_) * (H_ * DH_);   // 4M

    ushort* xb  = (ushort*)d_ws;          // 8 MB
    ushort* Wtq = xb + MN;                // 2 MB each
    ushort* Wtk = Wtq + 1024 * 1024;
    ushort* Wtv = Wtk + 1024 * 1024;
    ushort* Wto = Wtv + 1024 * 1024;
    ushort* Qb  = Wto + 1024 * 1024;      // 8 MB each
    ushort* Kb  = Qb + MN;
    ushort* Vt  = Kb + MN;
    ushort* Ob  = Vt + MN;

    convx_kernel<<<(int)(MN / 2048), 256, 0, stream>>>(x, xb);
    wconv_all_kernel<<<1024, 256, 0, stream>>>(Wq, Wk, Wv, Wo, Wtq, Wtk, Wtv, Wto);

    // fused QKV: grid = (4096/128) m-tiles x 24 n-tiles = 768 blocks (3/CU)
    gemm_bf16<1><<<768, 256, 0, stream>>>(xb, Wtq, Wtk, Wtv, bq, bk, bv, pos,
                                          (void*)Qb, (void*)Kb, (void*)Vt);

    // attention: 256 blocks x 512 threads (256 q-rows per block, 1 block/CU)
    attn_mfma_kernel<<<B_ * H_ * (S_ / 256), 512, 0, stream>>>(
        (const short*)Qb, (const short*)Kb, (const short*)Vt, vmask, Ob);

    // out-proj: grid = (4096/64) x 8 = 512 blocks (2/CU)
    gemm_bf16<0><<<512, 256, 0, stream>>>(Ob, Wto, nullptr, nullptr, bo, nullptr, nullptr,
                                          nullptr, (void*)out, nullptr, nullptr);
}